// Round 7
// baseline (221.767 us; speedup 1.0000x reference)
//
#include <hip/hip_runtime.h>
#include <hip/hip_cooperative_groups.h>

namespace cg = cooperative_groups;

// CosineAttention collapses to a linear map:
//   out[q] = (q_hat @ M + u) / (q_hat . s + n)
// with per-(b,h) moments over masked keys:
//   M[j][d] = sum_k m_k khat[k][j] V[k][d]   (64x64)
//   s[j]    = sum_k m_k khat[k][j]   u[d] = sum_k m_k V[k][d]   n = sum_k m_k
//
// R7: single cooperative kernel, 3 phases separated by grid.sync():
//   1) partial moments (bf16 MFMA, transposed LDS staging)  [R6 k_moments]
//   2) partial reduction -> fin (fp32 s/u/n) + finTh (bf16 M^T)
//   3) out = (qhat M + u) * rden, 128 rows/block, B-frags loaded once

#define S 4096
#define D 64
#define BH 16
#define FSTRIDE 4352
#define NE 4225          // 4096 (M) + 64 (s) + 64 (u) + 1 (n)
#define NCHM 32          // phase 1: 128 keys per block
#define KSTR 36          // staging dim-row stride in shorts (32 keys + 4 pad)
#define QSTR 72          // phase 3 Qst dim stride in shorts
#define SMEM_BYTES (8 * 64 * KSTR * 2 + 4 * 132 * 4)   // 38976

typedef __attribute__((ext_vector_type(8))) short short8;
typedef __attribute__((ext_vector_type(4))) short short4v;
typedef __attribute__((ext_vector_type(4))) float f32x4;

__device__ __forceinline__ float rl(float v, int l) {
    return __int_as_float(__builtin_amdgcn_readlane(__float_as_int(v), l));
}
__device__ __forceinline__ float bperm(float v, int srclane) {
    return __int_as_float(
        __builtin_amdgcn_ds_bpermute(srclane << 2, __float_as_int(v)));
}
__device__ __forceinline__ unsigned bf16h(float x) {
    unsigned u = __float_as_uint(x);
    u += 0x7FFF + ((u >> 16) & 1);          // round-nearest-even
    return u >> 16;
}

__global__ __launch_bounds__(256, 3) void k_fused(
    const float* __restrict__ Q, const float* __restrict__ K,
    const float* __restrict__ V, const int* __restrict__ mask,
    float* __restrict__ part, float* __restrict__ fin,
    unsigned short* __restrict__ finTh, float* __restrict__ out)
{
    __shared__ __align__(16) unsigned char smem_raw[SMEM_BYTES];
    cg::grid_group grid = cg::this_grid();

    const int tid  = threadIdx.x;
    const int lane = tid & 63;
    const int wave = tid >> 6;
    const int quad = lane >> 4;
    const int l15  = lane & 15;

    // ================= phase 1: partial moments (128 keys/block) =========
    {
        unsigned short* stag  = (unsigned short*)smem_raw;
        float*          sured = (float*)(smem_raw + 8 * 64 * KSTR * 2);
        float* red0 = (float*)smem_raw;
        float* red1 = red0 + 4096;

        const int bh    = blockIdx.x >> 5;
        const int chunk = blockIdx.x & 31;
        const int row0  = chunk * 128 + wave * 32;   // this wave's 32 keys

        const float* Kh = K + (size_t)bh * S * D;
        const float* Vh = V + (size_t)bh * S * D;
        const int*   mb = mask + (bh >> 3) * S;      // mask [B,1,1,S], H=8

        // phase A: 2 lanes per key (lane = c2*32 + r32), 1 shfl hop
        const int r32  = lane & 31;
        const int c2   = lane >> 5;
        const int rowA = row0 + r32;
        float ss = 0.f;
        {
            const float4* kp = (const float4*)(Kh + (size_t)rowA * D + c2 * 32);
            #pragma unroll
            for (int i = 0; i < 8; ++i) {
                float4 kv = kp[i];
                ss = fmaf(kv.x, kv.x, ss);
                ss = fmaf(kv.y, kv.y, ss);
                ss = fmaf(kv.z, kv.z, ss);
                ss = fmaf(kv.w, kv.w, ss);
            }
        }
        ss += __shfl_xor(ss, 32, 64);
        const float mval = (float)mb[rowA];
        const float minv = mval / fmaxf(sqrtf(ss), 1e-12f);  // masked -> 0
        float nw = mval;
        nw += __shfl_xor(nw, 1, 64);  nw += __shfl_xor(nw, 2, 64);
        nw += __shfl_xor(nw, 4, 64);  nw += __shfl_xor(nw, 8, 64);
        nw += __shfl_xor(nw, 16, 64); nw += __shfl_xor(nw, 32, 64);

        // staging: float4 loads; lane covers dims 4*l15..+3, key 8*quad+i
        unsigned short* Kst = stag + wave * (64 * KSTR);
        unsigned short* Vst = stag + 4 * (64 * KSTR) + wave * (64 * KSTR);
        unsigned* KstW = (unsigned*)Kst;
        unsigned* VstW = (unsigned*)Vst;

        float4 s4 = {0.f, 0.f, 0.f, 0.f}, u4 = {0.f, 0.f, 0.f, 0.f};
        unsigned kprev[4], vprev[4];
        #pragma unroll
        for (int i = 0; i < 8; ++i) {
            const int key = 8 * quad + i;
            const int row = row0 + key;
            float4 kf = *(const float4*)(Kh + (size_t)row * D + 4 * l15);
            float4 vf = *(const float4*)(Vh + (size_t)row * D + 4 * l15);
            float aj = bperm(minv, key);
            float mj = bperm(mval, key);
            float k0 = kf.x * aj, k1 = kf.y * aj, k2 = kf.z * aj, k3 = kf.w * aj;
            float v0 = vf.x * mj, v1 = vf.y * mj, v2 = vf.z * mj, v3 = vf.w * mj;
            s4.x += k0; s4.y += k1; s4.z += k2; s4.w += k3;
            u4.x += v0; u4.y += v1; u4.z += v2; u4.w += v3;
            unsigned kb0 = bf16h(k0), kb1 = bf16h(k1), kb2 = bf16h(k2), kb3 = bf16h(k3);
            unsigned vb0 = bf16h(v0), vb1 = bf16h(v1), vb2 = bf16h(v2), vb3 = bf16h(v3);
            if (i & 1) {    // write key pair (i-1, i) as one dword per dim
                const int base = 4 * quad + (i >> 1);
                KstW[(4 * l15 + 0) * 18 + base] = kprev[0] | (kb0 << 16);
                KstW[(4 * l15 + 1) * 18 + base] = kprev[1] | (kb1 << 16);
                KstW[(4 * l15 + 2) * 18 + base] = kprev[2] | (kb2 << 16);
                KstW[(4 * l15 + 3) * 18 + base] = kprev[3] | (kb3 << 16);
                VstW[(4 * l15 + 0) * 18 + base] = vprev[0] | (vb0 << 16);
                VstW[(4 * l15 + 1) * 18 + base] = vprev[1] | (vb1 << 16);
                VstW[(4 * l15 + 2) * 18 + base] = vprev[2] | (vb2 << 16);
                VstW[(4 * l15 + 3) * 18 + base] = vprev[3] | (vb3 << 16);
            } else {
                kprev[0] = kb0; kprev[1] = kb1; kprev[2] = kb2; kprev[3] = kb3;
                vprev[0] = vb0; vprev[1] = vb1; vprev[2] = vb2; vprev[3] = vb3;
            }
        }
        s4.x += __shfl_xor(s4.x, 16, 64); s4.x += __shfl_xor(s4.x, 32, 64);
        s4.y += __shfl_xor(s4.y, 16, 64); s4.y += __shfl_xor(s4.y, 32, 64);
        s4.z += __shfl_xor(s4.z, 16, 64); s4.z += __shfl_xor(s4.z, 32, 64);
        s4.w += __shfl_xor(s4.w, 16, 64); s4.w += __shfl_xor(s4.w, 32, 64);
        u4.x += __shfl_xor(u4.x, 16, 64); u4.x += __shfl_xor(u4.x, 32, 64);
        u4.y += __shfl_xor(u4.y, 16, 64); u4.y += __shfl_xor(u4.y, 32, 64);
        u4.z += __shfl_xor(u4.z, 16, 64); u4.z += __shfl_xor(u4.z, 32, 64);
        u4.w += __shfl_xor(u4.w, 16, 64); u4.w += __shfl_xor(u4.w, 32, 64);
        if (quad == 0) {
            sured[wave * 132 + 4 * l15 + 0]      = s4.x;
            sured[wave * 132 + 4 * l15 + 1]      = s4.y;
            sured[wave * 132 + 4 * l15 + 2]      = s4.z;
            sured[wave * 132 + 4 * l15 + 3]      = s4.w;
            sured[wave * 132 + 64 + 4 * l15 + 0] = u4.x;
            sured[wave * 132 + 64 + 4 * l15 + 1] = u4.y;
            sured[wave * 132 + 64 + 4 * l15 + 2] = u4.z;
            sured[wave * 132 + 64 + 4 * l15 + 3] = u4.w;
        }
        if (lane == 0) sured[wave * 132 + 128] = nw * 0.5f;
        __syncthreads();

        // fragments: MFMA over K=32 keys
        short8 af[4], bfr[4];
        #pragma unroll
        for (int t = 0; t < 4; ++t) {
            const unsigned short* ab = Kst + (t * 16 + l15) * KSTR + quad * 8;
            short4v a0 = *(const short4v*)ab;
            short4v a1 = *(const short4v*)(ab + 4);
            af[t] = __builtin_shufflevector(a0, a1, 0, 1, 2, 3, 4, 5, 6, 7);
            const unsigned short* bb = Vst + (t * 16 + l15) * KSTR + quad * 8;
            short4v b0 = *(const short4v*)bb;
            short4v b1 = *(const short4v*)(bb + 4);
            bfr[t] = __builtin_shufflevector(b0, b1, 0, 1, 2, 3, 4, 5, 6, 7);
        }
        f32x4 acc[4][4];
        #pragma unroll
        for (int tm = 0; tm < 4; ++tm)
            #pragma unroll
            for (int tn = 0; tn < 4; ++tn)
                acc[tm][tn] = (f32x4){0.f, 0.f, 0.f, 0.f};
        #pragma unroll
        for (int tn = 0; tn < 4; ++tn)
            #pragma unroll
            for (int tm = 0; tm < 4; ++tm)
                acc[tm][tn] = __builtin_amdgcn_mfma_f32_16x16x32_bf16(
                    af[tm], bfr[tn], acc[tm][tn], 0, 0, 0);
        __syncthreads();   // all frag reads done; staging may be overwritten

        // pairwise merge aliasing staging: waves 0/1 write, 2/3 add
        if (wave < 2) {
            float* rd = wave ? red1 : red0;
            #pragma unroll
            for (int tm = 0; tm < 4; ++tm)
                #pragma unroll
                for (int tn = 0; tn < 4; ++tn)
                    #pragma unroll
                    for (int rr = 0; rr < 4; ++rr)
                        rd[(tm * 16 + quad * 4 + rr) * 64 + tn * 16 + l15]
                            = acc[tm][tn][rr];
        }
        __syncthreads();
        if (wave >= 2) {
            float* rd = (wave == 3) ? red1 : red0;
            #pragma unroll
            for (int tm = 0; tm < 4; ++tm)
                #pragma unroll
                for (int tn = 0; tn < 4; ++tn)
                    #pragma unroll
                    for (int rr = 0; rr < 4; ++rr)
                        rd[(tm * 16 + quad * 4 + rr) * 64 + tn * 16 + l15]
                            += acc[tm][tn][rr];
        }
        __syncthreads();

        float* pp = part + ((size_t)bh * NCHM + chunk) * FSTRIDE;
        for (int i = tid; i < NE; i += 256) {
            float v;
            if (i < 4096)
                v = red0[i] + red1[i];
            else {
                int e = i - 4096;
                v = sured[e] + sured[132 + e] + sured[264 + e] + sured[396 + e];
            }
            pp[i] = v;
        }
    }

    grid.sync();

    // ================= phase 2: reduce partials ==========================
    {
        const int gtid = blockIdx.x * 256 + tid;      // 131072 >= 16*4225
        if (gtid < BH * NE) {
            const int bh = gtid / NE;
            const int e  = gtid - bh * NE;
            const float* p = part + (size_t)bh * NCHM * FSTRIDE + e;
            float a0 = 0.f, a1 = 0.f, a2 = 0.f, a3 = 0.f;
            #pragma unroll
            for (int c = 0; c < NCHM; c += 4) {
                a0 += p[(size_t)(c + 0) * FSTRIDE];
                a1 += p[(size_t)(c + 1) * FSTRIDE];
                a2 += p[(size_t)(c + 2) * FSTRIDE];
                a3 += p[(size_t)(c + 3) * FSTRIDE];
            }
            float v = (a0 + a1) + (a2 + a3);
            if (e < 4096)   // e = j*64 + d -> M^T[d][j] in bf16
                finTh[(size_t)bh * 4096 + (e & 63) * 64 + (e >> 6)]
                    = (unsigned short)bf16h(v);
            else
                fin[(size_t)bh * FSTRIDE + e] = v;
        }
    }

    grid.sync();

    // ================= phase 3: output, 128 rows/block ===================
    {
        unsigned short* Qst = (unsigned short*)smem_raw;

        const int bh = blockIdx.x >> 5;
        const float* fb = fin + (size_t)bh * FSTRIDE;
        const unsigned short* fT = finTh + (size_t)bh * 4096;
        const float* Qh = Q + (size_t)bh * S * D;
        float*       Oh = out + (size_t)bh * S * D;

        const float nval = fb[4224];
        float uo[4];
        #pragma unroll
        for (int tn = 0; tn < 4; ++tn) uo[tn] = fb[4160 + tn * 16 + l15];

        short8 bf0[4], bf1[4];   // B-frags loaded once, reused for 128 rows
        #pragma unroll
        for (int tn = 0; tn < 4; ++tn) {
            bf0[tn] = *(const short8*)(fT + (tn * 16 + l15) * 64 + quad * 8);
            bf1[tn] = *(const short8*)(fT + (tn * 16 + l15) * 64 + 32 + quad * 8);
        }

        #pragma unroll
        for (int cc = 0; cc < 2; ++cc) {
            const int row0 = ((blockIdx.x & 31) * 2 + cc) * 64;

            // phase A: 4 lanes per row (quad = d-chunk); 2 shfl hops
            const int rowA = row0 + wave * 16 + l15;
            float ss = 0.f, qs = 0.f;
            {
                const float4* qp = (const float4*)(Qh + (size_t)rowA * D + quad * 16);
                const float4* sp = (const float4*)(fb + 4096 + quad * 16);
                #pragma unroll
                for (int i = 0; i < 4; ++i) {
                    float4 qv = qp[i], sv = sp[i];
                    ss = fmaf(qv.x, qv.x, ss);
                    ss = fmaf(qv.y, qv.y, ss);
                    ss = fmaf(qv.z, qv.z, ss);
                    ss = fmaf(qv.w, qv.w, ss);
                    qs = fmaf(qv.x, sv.x, qs);
                    qs = fmaf(qv.y, sv.y, qs);
                    qs = fmaf(qv.z, sv.z, qs);
                    qs = fmaf(qv.w, sv.w, qs);
                }
            }
            ss += __shfl_xor(ss, 16, 64); ss += __shfl_xor(ss, 32, 64);
            qs += __shfl_xor(qs, 16, 64); qs += __shfl_xor(qs, 32, 64);
            const float invL = 1.f / fmaxf(sqrtf(ss), 1e-12f);
            const float rden = 1.f / fmaf(qs, invL, nval);   // row wave*16+l15

            // stage qhat bf16 [row][dim] (own-wave region only)
            unsigned short* Qw = Qst + wave * 16 * QSTR;
            #pragma unroll
            for (int r = 0; r < 16; ++r) {
                float qd = Qh[(size_t)(row0 + wave * 16 + r) * D + lane];
                Qw[r * QSTR + lane] = (unsigned short)bf16h(qd * rl(invL, r));
            }
            asm volatile("" ::: "memory");   // order stores vs frag loads

            short8 af0 = *(const short8*)(Qw + l15 * QSTR + quad * 8);
            short8 af1 = *(const short8*)(Qw + l15 * QSTR + 32 + quad * 8);

            f32x4 acc[4];
            #pragma unroll
            for (int tn = 0; tn < 4; ++tn) acc[tn] = (f32x4){0.f, 0.f, 0.f, 0.f};
            #pragma unroll
            for (int tn = 0; tn < 4; ++tn) {
                acc[tn] = __builtin_amdgcn_mfma_f32_16x16x32_bf16(af0, bf0[tn], acc[tn], 0, 0, 0);
                acc[tn] = __builtin_amdgcn_mfma_f32_16x16x32_bf16(af1, bf1[tn], acc[tn], 0, 0, 0);
            }

            // epilogue: C/D row = quad*4+rr, col = l15; rden via bpermute
            #pragma unroll
            for (int rr = 0; rr < 4; ++rr) {
                const int src = quad * 4 + rr;
                float rd = bperm(rden, src);
                const size_t row = row0 + wave * 16 + src;
                #pragma unroll
                for (int tn = 0; tn < 4; ++tn)
                    Oh[row * D + tn * 16 + l15] = (acc[tn][rr] + uo[tn]) * rd;
            }
            asm volatile("" ::: "memory");   // frag reads done before next cc's stores
        }
    }
}

extern "C" void kernel_launch(void* const* d_in, const int* in_sizes, int n_in,
                              void* d_out, int out_size, void* d_ws, size_t ws_size,
                              hipStream_t stream) {
    const float* Q    = (const float*)d_in[0];
    const float* K    = (const float*)d_in[1];
    const float* V    = (const float*)d_in[2];
    const int*   mask = (const int*)d_in[3];
    float* out = (float*)d_out;
    float* ws  = (float*)d_ws;

    float*          fin   = ws;                                           // BH*FSTRIDE f32
    unsigned short* finTh = (unsigned short*)(ws + (size_t)BH * FSTRIDE); // BH*4096 bf16
    float*          part  = (float*)((char*)finTh + (size_t)BH * 4096 * 2);

    void* args[] = {(void*)&Q, (void*)&K, (void*)&V, (void*)&mask,
                    (void*)&part, (void*)&fin, (void*)&finTh, (void*)&out};
    hipLaunchCooperativeKernel((const void*)k_fused, dim3(BH * NCHM), dim3(256),
                               args, 0, stream);
}

// Round 8
// 106.768 us; speedup vs baseline: 2.0771x; 2.0771x over previous
//
#include <hip/hip_runtime.h>

// CosineAttention collapses to a linear map:
//   out[q] = (q_hat @ M + u) / (q_hat . s + n)
// with per-(b,h) moments over masked keys:
//   M[j][d] = sum_k m_k khat[k][j] V[k][d]   (64x64)
//   s[j]    = sum_k m_k khat[k][j]   u[d] = sum_k m_k V[k][d]   n = sum_k m_k
//
// R8 (revert R7 coop fusion — grid.sync spin cost ~40us/sync):
//  k1: blocks 0-511 = R6 moments (bf16-M partials); blocks 512-1023 = Q-norm
//      precompute (invQ), overlapped in the same launch.
//  k2: reduce partials -> fin (fp32 s/u/n) + finTh (bf16 M^T and bf16 s).
//  k3: no fp32 phase A; denominator via extra s-column MFMA; 128 rows/block.

#define S 4096
#define D 64
#define BH 16
#define FSTRIDE 4352
#define NE 4225          // 4096 (M) + 64 (s) + 64 (u) + 1 (n)
#define NCHM 32          // moments: 128 keys per block
#define KSTR 36          // staging dim-row stride in shorts (32 keys + 4 pad)
#define QSTR 72          // k3 Qst dim stride in shorts
#define PSTR 8832        // partial stride BYTES: 4096 u16 (M) + 129 f32, padded
#define FTSTR 4224       // finTh per-bh stride in shorts: 4096 M^T + 64 s + pad

typedef __attribute__((ext_vector_type(8))) short short8;
typedef __attribute__((ext_vector_type(4))) short short4v;
typedef __attribute__((ext_vector_type(4))) float f32x4;

__device__ __forceinline__ float rl(float v, int l) {
    return __int_as_float(__builtin_amdgcn_readlane(__float_as_int(v), l));
}
__device__ __forceinline__ float bperm(float v, int srclane) {
    return __int_as_float(
        __builtin_amdgcn_ds_bpermute(srclane << 2, __float_as_int(v)));
}
__device__ __forceinline__ unsigned bf16h(float x) {
    unsigned u = __float_as_uint(x);
    u += 0x7FFF + ((u >> 16) & 1);          // round-nearest-even
    return u >> 16;
}
__device__ __forceinline__ float bf16f(unsigned short h) {
    return __uint_as_float(((unsigned)h) << 16);
}

// ------ kernel 1: [0,512) partial moments | [512,1024) Q-norm precompute --
__global__ __launch_bounds__(256, 4) void k_moments(
    const float* __restrict__ Q, const float* __restrict__ K,
    const float* __restrict__ V, const int* __restrict__ mask,
    char* __restrict__ part, float* __restrict__ invQ)
{
    __shared__ unsigned short stag[8 * 64 * KSTR];   // 36864 B
    __shared__ float sured[4 * 132];
    float* red0 = (float*)stag;                      // merge aliases staging
    float* red1 = red0 + 4096;

    const int tid  = threadIdx.x;
    const int lane = tid & 63;
    const int wave = tid >> 6;
    const int quad = lane >> 4;
    const int l15  = lane & 15;

    if (blockIdx.x >= 512) {             // ---------- Q-norm half ----------
        const int b2 = blockIdx.x - 512;
        const int bh = b2 >> 5, chunk = b2 & 31;
        const float* Qh = Q + (size_t)bh * S * D;
        const int r32 = lane & 31, c2 = lane >> 5;
        const int row = chunk * 128 + wave * 32 + r32;
        float ss = 0.f;
        const float4* qp = (const float4*)(Qh + (size_t)row * D + c2 * 32);
        #pragma unroll
        for (int i = 0; i < 8; ++i) {
            float4 qv = qp[i];
            ss = fmaf(qv.x, qv.x, ss);
            ss = fmaf(qv.y, qv.y, ss);
            ss = fmaf(qv.z, qv.z, ss);
            ss = fmaf(qv.w, qv.w, ss);
        }
        ss += __shfl_xor(ss, 32, 64);
        float inv = 1.f / fmaxf(sqrtf(ss), 1e-12f);
        if (c2 == 0) invQ[(size_t)bh * S + row] = inv;
        return;
    }

    // --------------------------- moments half ----------------------------
    const int bh    = blockIdx.x >> 5;
    const int chunk = blockIdx.x & 31;
    const int row0  = chunk * 128 + wave * 32;       // this wave's 32 keys

    const float* Kh = K + (size_t)bh * S * D;
    const float* Vh = V + (size_t)bh * S * D;
    const int*   mb = mask + (bh >> 3) * S;          // mask [B,1,1,S], H=8

    // phase A: 2 lanes per key, 1 shfl hop
    const int r32 = lane & 31, c2 = lane >> 5;
    const int rowA = row0 + r32;
    float ss = 0.f;
    {
        const float4* kp = (const float4*)(Kh + (size_t)rowA * D + c2 * 32);
        #pragma unroll
        for (int i = 0; i < 8; ++i) {
            float4 kv = kp[i];
            ss = fmaf(kv.x, kv.x, ss);
            ss = fmaf(kv.y, kv.y, ss);
            ss = fmaf(kv.z, kv.z, ss);
            ss = fmaf(kv.w, kv.w, ss);
        }
    }
    ss += __shfl_xor(ss, 32, 64);
    const float mval = (float)mb[rowA];
    const float minv = mval / fmaxf(sqrtf(ss), 1e-12f);  // masked -> 0
    float nw = mval;
    nw += __shfl_xor(nw, 1, 64);  nw += __shfl_xor(nw, 2, 64);
    nw += __shfl_xor(nw, 4, 64);  nw += __shfl_xor(nw, 8, 64);
    nw += __shfl_xor(nw, 16, 64); nw += __shfl_xor(nw, 32, 64);

    // staging: float4 loads; lane covers dims 4*l15..+3, key 8*quad+i
    unsigned short* Kst = stag + wave * (64 * KSTR);
    unsigned short* Vst = stag + 4 * (64 * KSTR) + wave * (64 * KSTR);
    unsigned* KstW = (unsigned*)Kst;
    unsigned* VstW = (unsigned*)Vst;

    float4 s4 = {0.f, 0.f, 0.f, 0.f}, u4 = {0.f, 0.f, 0.f, 0.f};
    unsigned kprev[4], vprev[4];
    #pragma unroll
    for (int i = 0; i < 8; ++i) {
        const int key = 8 * quad + i;
        const int row = row0 + key;
        float4 kf = *(const float4*)(Kh + (size_t)row * D + 4 * l15);
        float4 vf = *(const float4*)(Vh + (size_t)row * D + 4 * l15);
        float aj = bperm(minv, key);
        float mj = bperm(mval, key);
        float k0 = kf.x * aj, k1 = kf.y * aj, k2 = kf.z * aj, k3 = kf.w * aj;
        float v0 = vf.x * mj, v1 = vf.y * mj, v2 = vf.z * mj, v3 = vf.w * mj;
        s4.x += k0; s4.y += k1; s4.z += k2; s4.w += k3;
        u4.x += v0; u4.y += v1; u4.z += v2; u4.w += v3;
        unsigned kb0 = bf16h(k0), kb1 = bf16h(k1), kb2 = bf16h(k2), kb3 = bf16h(k3);
        unsigned vb0 = bf16h(v0), vb1 = bf16h(v1), vb2 = bf16h(v2), vb3 = bf16h(v3);
        if (i & 1) {
            const int base = 4 * quad + (i >> 1);
            KstW[(4 * l15 + 0) * 18 + base] = kprev[0] | (kb0 << 16);
            KstW[(4 * l15 + 1) * 18 + base] = kprev[1] | (kb1 << 16);
            KstW[(4 * l15 + 2) * 18 + base] = kprev[2] | (kb2 << 16);
            KstW[(4 * l15 + 3) * 18 + base] = kprev[3] | (kb3 << 16);
            VstW[(4 * l15 + 0) * 18 + base] = vprev[0] | (vb0 << 16);
            VstW[(4 * l15 + 1) * 18 + base] = vprev[1] | (vb1 << 16);
            VstW[(4 * l15 + 2) * 18 + base] = vprev[2] | (vb2 << 16);
            VstW[(4 * l15 + 3) * 18 + base] = vprev[3] | (vb3 << 16);
        } else {
            kprev[0] = kb0; kprev[1] = kb1; kprev[2] = kb2; kprev[3] = kb3;
            vprev[0] = vb0; vprev[1] = vb1; vprev[2] = vb2; vprev[3] = vb3;
        }
    }
    s4.x += __shfl_xor(s4.x, 16, 64); s4.x += __shfl_xor(s4.x, 32, 64);
    s4.y += __shfl_xor(s4.y, 16, 64); s4.y += __shfl_xor(s4.y, 32, 64);
    s4.z += __shfl_xor(s4.z, 16, 64); s4.z += __shfl_xor(s4.z, 32, 64);
    s4.w += __shfl_xor(s4.w, 16, 64); s4.w += __shfl_xor(s4.w, 32, 64);
    u4.x += __shfl_xor(u4.x, 16, 64); u4.x += __shfl_xor(u4.x, 32, 64);
    u4.y += __shfl_xor(u4.y, 16, 64); u4.y += __shfl_xor(u4.y, 32, 64);
    u4.z += __shfl_xor(u4.z, 16, 64); u4.z += __shfl_xor(u4.z, 32, 64);
    u4.w += __shfl_xor(u4.w, 16, 64); u4.w += __shfl_xor(u4.w, 32, 64);
    if (quad == 0) {
        sured[wave * 132 + 4 * l15 + 0]      = s4.x;
        sured[wave * 132 + 4 * l15 + 1]      = s4.y;
        sured[wave * 132 + 4 * l15 + 2]      = s4.z;
        sured[wave * 132 + 4 * l15 + 3]      = s4.w;
        sured[wave * 132 + 64 + 4 * l15 + 0] = u4.x;
        sured[wave * 132 + 64 + 4 * l15 + 1] = u4.y;
        sured[wave * 132 + 64 + 4 * l15 + 2] = u4.z;
        sured[wave * 132 + 64 + 4 * l15 + 3] = u4.w;
    }
    if (lane == 0) sured[wave * 132 + 128] = nw * 0.5f;
    __syncthreads();

    // fragments: MFMA over K=32 keys
    short8 af[4], bfr[4];
    #pragma unroll
    for (int t = 0; t < 4; ++t) {
        const unsigned short* ab = Kst + (t * 16 + l15) * KSTR + quad * 8;
        short4v a0 = *(const short4v*)ab;
        short4v a1 = *(const short4v*)(ab + 4);
        af[t] = __builtin_shufflevector(a0, a1, 0, 1, 2, 3, 4, 5, 6, 7);
        const unsigned short* bb = Vst + (t * 16 + l15) * KSTR + quad * 8;
        short4v b0 = *(const short4v*)bb;
        short4v b1 = *(const short4v*)(bb + 4);
        bfr[t] = __builtin_shufflevector(b0, b1, 0, 1, 2, 3, 4, 5, 6, 7);
    }
    f32x4 acc[4][4];
    #pragma unroll
    for (int tm = 0; tm < 4; ++tm)
        #pragma unroll
        for (int tn = 0; tn < 4; ++tn)
            acc[tm][tn] = (f32x4){0.f, 0.f, 0.f, 0.f};
    #pragma unroll
    for (int tn = 0; tn < 4; ++tn)
        #pragma unroll
        for (int tm = 0; tm < 4; ++tm)
            acc[tm][tn] = __builtin_amdgcn_mfma_f32_16x16x32_bf16(
                af[tm], bfr[tn], acc[tm][tn], 0, 0, 0);
    __syncthreads();

    // pairwise merge aliasing staging: waves 0/1 write, 2/3 add
    if (wave < 2) {
        float* rd = wave ? red1 : red0;
        #pragma unroll
        for (int tm = 0; tm < 4; ++tm)
            #pragma unroll
            for (int tn = 0; tn < 4; ++tn)
                #pragma unroll
                for (int rr = 0; rr < 4; ++rr)
                    rd[(tm * 16 + quad * 4 + rr) * 64 + tn * 16 + l15]
                        = acc[tm][tn][rr];
    }
    __syncthreads();
    if (wave >= 2) {
        float* rd = (wave == 3) ? red1 : red0;
        #pragma unroll
        for (int tm = 0; tm < 4; ++tm)
            #pragma unroll
            for (int tn = 0; tn < 4; ++tn)
                #pragma unroll
                for (int rr = 0; rr < 4; ++rr)
                    rd[(tm * 16 + quad * 4 + rr) * 64 + tn * 16 + l15]
                        += acc[tm][tn][rr];
    }
    __syncthreads();

    char* pb = part + ((size_t)bh * NCHM + chunk) * PSTR;
    unsigned short* pm = (unsigned short*)pb;
    float* psu = (float*)(pb + 8192);
    for (int i = tid; i < NE; i += 256) {
        if (i < 4096)
            pm[i] = (unsigned short)bf16h(red0[i] + red1[i]);
        else {
            int e = i - 4096;
            psu[e] = sured[e] + sured[132 + e] + sured[264 + e] + sured[396 + e];
        }
    }
}

// ------ kernel 2: reduce partials -> fin (fp32) + finTh (bf16 M^T, s) ----
__global__ __launch_bounds__(256) void k_reduce(
    const char* __restrict__ part, float* __restrict__ fin,
    unsigned short* __restrict__ finTh)
{
    const int bh = blockIdx.x;
    const int e  = blockIdx.y * 256 + threadIdx.x;
    if (e >= NE) return;
    const char* pb = part + (size_t)bh * NCHM * PSTR;
    if (e < 4096) {
        float a0 = 0.f, a1 = 0.f, a2 = 0.f, a3 = 0.f;
        #pragma unroll
        for (int c = 0; c < NCHM; c += 4) {
            a0 += bf16f(*(const unsigned short*)(pb + (size_t)(c + 0) * PSTR + 2 * e));
            a1 += bf16f(*(const unsigned short*)(pb + (size_t)(c + 1) * PSTR + 2 * e));
            a2 += bf16f(*(const unsigned short*)(pb + (size_t)(c + 2) * PSTR + 2 * e));
            a3 += bf16f(*(const unsigned short*)(pb + (size_t)(c + 3) * PSTR + 2 * e));
        }
        float v = (a0 + a1) + (a2 + a3);
        finTh[(size_t)bh * FTSTR + (e & 63) * 64 + (e >> 6)] = (unsigned short)bf16h(v);
    } else {
        const int eo = e - 4096;
        float a0 = 0.f, a1 = 0.f, a2 = 0.f, a3 = 0.f;
        #pragma unroll
        for (int c = 0; c < NCHM; c += 4) {
            a0 += *(const float*)(pb + (size_t)(c + 0) * PSTR + 8192 + 4 * eo);
            a1 += *(const float*)(pb + (size_t)(c + 1) * PSTR + 8192 + 4 * eo);
            a2 += *(const float*)(pb + (size_t)(c + 2) * PSTR + 8192 + 4 * eo);
            a3 += *(const float*)(pb + (size_t)(c + 3) * PSTR + 8192 + 4 * eo);
        }
        float v = (a0 + a1) + (a2 + a3);
        fin[(size_t)bh * FSTRIDE + e] = v;
        if (eo < 64)    // bf16 s for k3's denominator MFMA column
            finTh[(size_t)bh * FTSTR + 4096 + eo] = (unsigned short)bf16h(v);
    }
}

// ------ kernel 3: out = (qhat M + u) / (qhat.s + n), den via MFMA --------
// grid 512 blocks x 256; 128 rows/block; B-frags loaded once.
__global__ __launch_bounds__(256) void k_out(
    const float* __restrict__ Q, const float* __restrict__ fin,
    const unsigned short* __restrict__ finTh, const float* __restrict__ invQ,
    float* __restrict__ out)
{
    __shared__ unsigned short Qst[4 * 16 * QSTR];

    const int tid  = threadIdx.x;
    const int lane = tid & 63;
    const int wave = tid >> 6;
    const int quad = lane >> 4;
    const int l15  = lane & 15;

    const int bh  = blockIdx.x >> 5;
    const int c32 = blockIdx.x & 31;

    const float* fb = fin + (size_t)bh * FSTRIDE;
    const unsigned short* fT = finTh + (size_t)bh * FTSTR;
    const float* Qh = Q + (size_t)bh * S * D;
    float*       Oh = out + (size_t)bh * S * D;

    const float nval = fb[4224];
    float uo[4];
    #pragma unroll
    for (int tn = 0; tn < 4; ++tn) uo[tn] = fb[4160 + tn * 16 + l15];

    short8 bf0[4], bf1[4];              // M^T B-frags, loaded once
    #pragma unroll
    for (int tn = 0; tn < 4; ++tn) {
        bf0[tn] = *(const short8*)(fT + (tn * 16 + l15) * 64 + quad * 8);
        bf1[tn] = *(const short8*)(fT + (tn * 16 + l15) * 64 + 32 + quad * 8);
    }
    // s-column B-frags: col 0 = s, other cols 0
    short8 sz = {0, 0, 0, 0, 0, 0, 0, 0};
    short8 sv0 = *(const short8*)(fT + 4096 + quad * 8);
    short8 sv1 = *(const short8*)(fT + 4096 + 32 + quad * 8);
    short8 bs0 = (l15 == 0) ? sv0 : sz;
    short8 bs1 = (l15 == 0) ? sv1 : sz;

    unsigned short* Qw = Qst + wave * 16 * QSTR;

    #pragma unroll
    for (int cc = 0; cc < 2; ++cc) {
        const int row0w = (c32 * 2 + cc) * 64 + wave * 16;
        const float invv = invQ[(size_t)bh * S + row0w + l15];

        // stage qhat bf16 [row][dim]: 4 iters, float4 loads, b64 LDS writes
        #pragma unroll
        for (int i = 0; i < 4; ++i) {
            const int r = 4 * quad + i;
            float4 qv = *(const float4*)(Qh + (size_t)(row0w + r) * D + 4 * l15);
            float iq = bperm(invv, r);
            unsigned b0 = bf16h(qv.x * iq), b1 = bf16h(qv.y * iq);
            unsigned b2 = bf16h(qv.z * iq), b3 = bf16h(qv.w * iq);
            uint2 w; w.x = b0 | (b1 << 16); w.y = b2 | (b3 << 16);
            *(uint2*)(Qw + r * QSTR + 4 * l15) = w;
        }
        asm volatile("" ::: "memory");

        short8 af0 = *(const short8*)(Qw + l15 * QSTR + quad * 8);
        short8 af1 = *(const short8*)(Qw + l15 * QSTR + 32 + quad * 8);

        f32x4 acc[4], acc5;
        #pragma unroll
        for (int tn = 0; tn < 4; ++tn) acc[tn] = (f32x4){0.f, 0.f, 0.f, 0.f};
        acc5 = (f32x4){0.f, 0.f, 0.f, 0.f};
        #pragma unroll
        for (int tn = 0; tn < 4; ++tn) {
            acc[tn] = __builtin_amdgcn_mfma_f32_16x16x32_bf16(af0, bf0[tn], acc[tn], 0, 0, 0);
            acc[tn] = __builtin_amdgcn_mfma_f32_16x16x32_bf16(af1, bf1[tn], acc[tn], 0, 0, 0);
        }
        acc5 = __builtin_amdgcn_mfma_f32_16x16x32_bf16(af0, bs0, acc5, 0, 0, 0);
        acc5 = __builtin_amdgcn_mfma_f32_16x16x32_bf16(af1, bs1, acc5, 0, 0, 0);

        // epilogue: C/D row = quad*4+rr, col = l15; den from acc5 col 0
        #pragma unroll
        for (int rr = 0; rr < 4; ++rr) {
            float den = bperm(acc5[rr], 16 * quad) + nval;
            float rd = 1.f / den;
            const size_t row = row0w + quad * 4 + rr;
            #pragma unroll
            for (int tn = 0; tn < 4; ++tn)
                Oh[row * D + tn * 16 + l15] = (acc[tn][rr] + uo[tn]) * rd;
        }
        asm volatile("" ::: "memory");   // frag reads done before next cc stores
    }
}

extern "C" void kernel_launch(void* const* d_in, const int* in_sizes, int n_in,
                              void* d_out, int out_size, void* d_ws, size_t ws_size,
                              hipStream_t stream) {
    const float* Q    = (const float*)d_in[0];
    const float* K    = (const float*)d_in[1];
    const float* V    = (const float*)d_in[2];
    const int*   mask = (const int*)d_in[3];
    float* out = (float*)d_out;
    char*  ws  = (char*)d_ws;

    float*          fin   = (float*)ws;                          // BH*FSTRIDE f32
    unsigned short* finTh = (unsigned short*)(ws + (size_t)BH * FSTRIDE * 4);
    float*          invQ  = (float*)((char*)finTh + (size_t)BH * FTSTR * 2);
    char*           part  = (char*)invQ + (size_t)BH * S * 4;    // BH*NCHM*PSTR

    k_moments<<<dim3(1024), 256, 0, stream>>>(Q, K, V, mask, part, invQ);
    k_reduce <<<dim3(BH, (NE + 255) / 256), 256, 0, stream>>>(part, fin, finTh);
    k_out    <<<dim3(512), 256, 0, stream>>>(Q, fin, finTh, invQ, out);
}